// Round 3
// baseline (7887.787 us; speedup 1.0000x reference)
//
#include <hip/hip_runtime.h>
#include <hip/hip_bf16.h>
#include <stdint.h>

#define NCELL 2048
#define UG    196
#define DIN   384
#define DH    512
#define DOUT  256
#define EPSV  1e-5f

// ws layout (bytes)
#define AB_BYTES   205520896ull            // 401408*256*2  (a as bf16)
#define QRAW_OFF   AB_BYTES
#define QRAW_BYTES 2097152ull              // 2048*256*4    (raw query rows)
#define SIM_OFF    (QRAW_OFF + QRAW_BYTES)
#define SIM_BYTES  1605632ull              // 2048*196*4    (fp32 sims)
#define QNORM_OFF  (SIM_OFF + SIM_BYTES)   // 2048*4

static __device__ __forceinline__ unsigned short f2bf_bits(float x) {
    return __builtin_bit_cast(unsigned short, __float2bfloat16(x));
}

// ---------------- Kernel 1a: query rows (raw) + norms ----------------
__global__ __launch_bounds__(256)
void k_query(const float* __restrict__ patches, const int* __restrict__ patch_ids,
             const int* __restrict__ offsets,
             const float* __restrict__ W1, const float* __restrict__ b1,
             const float* __restrict__ W2, const float* __restrict__ b2,
             float* __restrict__ qraw, float* __restrict__ qnorm)
{
    __shared__ float sA[8 * DIN];
    __shared__ float sH[8 * DH];
    __shared__ float sPart[4 * 8];
    __shared__ int   sSrc[8];
    const int t  = threadIdx.x;
    const int nb = blockIdx.x * 8;
    if (t < 8) {
        int n  = nb + t;
        int ox = offsets[2 * n + 0];
        int oy = offsets[2 * n + 1];
        int it = min(max(7 + oy, 0), 13);
        int jt = min(max(7 + ox, 0), 13);
        sSrc[t] = patch_ids[n] * 196 + it * 14 + jt;
    }
    __syncthreads();
    #pragma unroll
    for (int i = 0; i < 3; ++i) {
        int fi = t + 256 * i;               // < 768 = 8 rows * 96 float4
        int r = fi / 96, c4 = fi % 96;
        const float4 v = ((const float4*)(patches + (size_t)sSrc[r] * DIN))[c4];
        ((float4*)(sA + r * DIN))[c4] = v;
    }
    __syncthreads();
    float h0[8], h1[8];
    {
        const float bb0 = b1[t], bb1 = b1[t + 256];
        #pragma unroll
        for (int r = 0; r < 8; ++r) { h0[r] = bb0; h1[r] = bb1; }
    }
    for (int k = 0; k < DIN; ++k) {
        const float w0 = W1[k * DH + t];
        const float w1 = W1[k * DH + t + 256];
        #pragma unroll
        for (int r = 0; r < 8; ++r) {
            const float av = sA[r * DIN + k];
            h0[r] = fmaf(av, w0, h0[r]);
            h1[r] = fmaf(av, w1, h1[r]);
        }
    }
    #pragma unroll
    for (int r = 0; r < 8; ++r) {
        float v0 = h0[r]; v0 = v0 >= 0.f ? v0 : 0.01f * v0;
        float v1 = h1[r]; v1 = v1 >= 0.f ? v1 : 0.01f * v1;
        sH[r * DH + t]       = v0;
        sH[r * DH + t + 256] = v1;
    }
    __syncthreads();
    float a8[8];
    {
        const float bb = b2[t];
        #pragma unroll
        for (int r = 0; r < 8; ++r) a8[r] = bb;
    }
    for (int k = 0; k < DH; ++k) {
        const float w = W2[k * DOUT + t];
        #pragma unroll
        for (int r = 0; r < 8; ++r) a8[r] = fmaf(sH[r * DH + k], w, a8[r]);
    }
    const int wid = t >> 6;
    #pragma unroll
    for (int r = 0; r < 8; ++r) {
        float p = a8[r] * a8[r];
        #pragma unroll
        for (int m = 1; m < 64; m <<= 1) p += __shfl_xor(p, m);
        if ((t & 63) == 0) sPart[wid * 8 + r] = p;
    }
    __syncthreads();
    if (t < 8) {
        float s = sPart[t] + sPart[8 + t] + sPart[16 + t] + sPart[24 + t];
        qnorm[nb + t] = fmaxf(sqrtf(s), 1e-12f);
    }
    #pragma unroll
    for (int r = 0; r < 8; ++r)
        qraw[(size_t)(nb + r) * DOUT + t] = a8[r];
}

// -------- Kernel 1b: fused gather + MLP + sim epilogue + bf16 a ------
// v2: vectorized LDS operands (b128 W reads, float4 A broadcasts over 4 k),
//     register-prefetched W chunks (issue-early / write-late).
__global__ __launch_bounds__(256)
void k_mlp(const float* __restrict__ patches, const int* __restrict__ patch_ids,
           const float* __restrict__ W1, const float* __restrict__ b1,
           const float* __restrict__ W2, const float* __restrict__ b2,
           const float* __restrict__ qraw, const float* __restrict__ qnorm,
           __hip_bfloat16* __restrict__ ab, float* __restrict__ sims)
{
    __shared__ float sBuf[32 * DH];    // phase1: A tile 32x384 ; phase2: H tile 32x512
    __shared__ float sW[4096];         // W chunk (16KB)
    const int t  = threadIdx.x;
    const int cg = t & 63;
    const int rg = t >> 6;
    const int R0 = blockIdx.x * 32;

    // ---- stage A tile (32 rows x 384) ----
    #pragma unroll
    for (int i = 0; i < 12; ++i) {
        int fi = t + 256 * i;           // < 3072 = 32 rows * 96 float4
        int r  = fi / 96, c4 = fi % 96;
        int Rg = R0 + r;
        int n  = Rg / 196;
        int u  = Rg - n * 196;
        const float4 v =
            ((const float4*)(patches + ((size_t)patch_ids[n] * 196 + u) * DIN))[c4];
        ((float4*)(sBuf + r * DIN))[c4] = v;
    }

    float acc1[8][8];                  // 8 rows x (2 col-groups x 4 consecutive cols)
    #pragma unroll
    for (int i = 0; i < 8; ++i)
        #pragma unroll
        for (int j = 0; j < 8; ++j) acc1[i][j] = 0.f;

    float4 wreg[4];
    #pragma unroll
    for (int i = 0; i < 4; ++i)
        wreg[i] = ((const float4*)W1)[t + 256 * i];   // chunk 0 prefetch

    // GEMM1: 32x512 += A(32x384) @ W1(384x512), K-chunks of 8
    for (int kc = 0; kc < 48; ++kc) {
        __syncthreads();               // prev chunk fully consumed (and A staged, iter 0)
        #pragma unroll
        for (int i = 0; i < 4; ++i)
            ((float4*)sW)[t + 256 * i] = wreg[i];
        if (kc < 47) {
            const float4* src = (const float4*)(W1 + (size_t)(kc + 1) * 8 * DH);
            #pragma unroll
            for (int i = 0; i < 4; ++i) wreg[i] = src[t + 256 * i];
        }
        __syncthreads();
        #pragma unroll
        for (int kg = 0; kg < 2; ++kg) {
            float4 av4[8];
            #pragma unroll
            for (int i = 0; i < 8; ++i)
                av4[i] = *(const float4*)(sBuf + (rg * 8 + i) * DIN + kc * 8 + kg * 4);
            #pragma unroll
            for (int kk = 0; kk < 4; ++kk) {
                const float4 w0 = *(const float4*)(sW + (kg * 4 + kk) * DH + cg * 4);
                const float4 w1 = *(const float4*)(sW + (kg * 4 + kk) * DH + 256 + cg * 4);
                #pragma unroll
                for (int i = 0; i < 8; ++i) {
                    const float a = (kk == 0) ? av4[i].x : (kk == 1) ? av4[i].y
                                  : (kk == 2) ? av4[i].z : av4[i].w;
                    acc1[i][0] = fmaf(a, w0.x, acc1[i][0]);
                    acc1[i][1] = fmaf(a, w0.y, acc1[i][1]);
                    acc1[i][2] = fmaf(a, w0.z, acc1[i][2]);
                    acc1[i][3] = fmaf(a, w0.w, acc1[i][3]);
                    acc1[i][4] = fmaf(a, w1.x, acc1[i][4]);
                    acc1[i][5] = fmaf(a, w1.y, acc1[i][5]);
                    acc1[i][6] = fmaf(a, w1.z, acc1[i][6]);
                    acc1[i][7] = fmaf(a, w1.w, acc1[i][7]);
                }
            }
        }
    }

    // bias + LeakyReLU, prefetch first W2 chunk, store H into sBuf
    const float4 b1f0 = ((const float4*)b1)[cg];
    const float4 b1f1 = ((const float4*)b1)[64 + cg];
    #pragma unroll
    for (int i = 0; i < 4; ++i)
        wreg[i] = ((const float4*)W2)[t + 256 * i];   // W2 chunk 0 prefetch
    __syncthreads();                    // done reading A from sBuf
    #pragma unroll
    for (int i = 0; i < 8; ++i) {
        float4 v0, v1;
        v0.x = acc1[i][0] + b1f0.x; v0.y = acc1[i][1] + b1f0.y;
        v0.z = acc1[i][2] + b1f0.z; v0.w = acc1[i][3] + b1f0.w;
        v1.x = acc1[i][4] + b1f1.x; v1.y = acc1[i][5] + b1f1.y;
        v1.z = acc1[i][6] + b1f1.z; v1.w = acc1[i][7] + b1f1.w;
        v0.x = v0.x >= 0.f ? v0.x : 0.01f * v0.x;
        v0.y = v0.y >= 0.f ? v0.y : 0.01f * v0.y;
        v0.z = v0.z >= 0.f ? v0.z : 0.01f * v0.z;
        v0.w = v0.w >= 0.f ? v0.w : 0.01f * v0.w;
        v1.x = v1.x >= 0.f ? v1.x : 0.01f * v1.x;
        v1.y = v1.y >= 0.f ? v1.y : 0.01f * v1.y;
        v1.z = v1.z >= 0.f ? v1.z : 0.01f * v1.z;
        v1.w = v1.w >= 0.f ? v1.w : 0.01f * v1.w;
        *(float4*)(sBuf + (rg * 8 + i) * DH + cg * 4)       = v0;
        *(float4*)(sBuf + (rg * 8 + i) * DH + 256 + cg * 4) = v1;
    }

    float acc2[8][4];                  // 8 rows x 4 consecutive cols (c = cg*4+j)
    #pragma unroll
    for (int i = 0; i < 8; ++i)
        #pragma unroll
        for (int j = 0; j < 4; ++j) acc2[i][j] = 0.f;

    // GEMM2: 32x256 += H(32x512) @ W2(512x256), K-chunks of 16
    for (int kc = 0; kc < 32; ++kc) {
        __syncthreads();               // prev chunk consumed (iter 0: H writes drained)
        #pragma unroll
        for (int i = 0; i < 4; ++i)
            ((float4*)sW)[t + 256 * i] = wreg[i];
        if (kc < 31) {
            const float4* src = (const float4*)(W2 + (size_t)(kc + 1) * 16 * DOUT);
            #pragma unroll
            for (int i = 0; i < 4; ++i) wreg[i] = src[t + 256 * i];
        }
        __syncthreads();
        #pragma unroll
        for (int kg = 0; kg < 4; ++kg) {
            float4 av4[8];
            #pragma unroll
            for (int i = 0; i < 8; ++i)
                av4[i] = *(const float4*)(sBuf + (rg * 8 + i) * DH + kc * 16 + kg * 4);
            #pragma unroll
            for (int kk = 0; kk < 4; ++kk) {
                const float4 w0 = *(const float4*)(sW + (kg * 4 + kk) * DOUT + cg * 4);
                #pragma unroll
                for (int i = 0; i < 8; ++i) {
                    const float a = (kk == 0) ? av4[i].x : (kk == 1) ? av4[i].y
                                  : (kk == 2) ? av4[i].z : av4[i].w;
                    acc2[i][0] = fmaf(a, w0.x, acc2[i][0]);
                    acc2[i][1] = fmaf(a, w0.y, acc2[i][1]);
                    acc2[i][2] = fmaf(a, w0.z, acc2[i][2]);
                    acc2[i][3] = fmaf(a, w0.w, acc2[i][3]);
                }
            }
        }
    }

    {
        const float4 b2f = ((const float4*)b2)[cg];
        #pragma unroll
        for (int i = 0; i < 8; ++i) {
            acc2[i][0] += b2f.x; acc2[i][1] += b2f.y;
            acc2[i][2] += b2f.z; acc2[i][3] += b2f.w;
        }
    }

    // epilogue: fp32 cosine sim vs query + bf16 store of a
    #pragma unroll
    for (int i = 0; i < 8; ++i) {
        const int Rg = R0 + rg * 8 + i;
        const int n  = Rg / 196;
        const float4 qv = ((const float4*)(qraw + (size_t)n * DOUT))[cg];
        float nrm = 0.f, dot = 0.f;
        nrm = fmaf(acc2[i][0], acc2[i][0], nrm); dot = fmaf(acc2[i][0], qv.x, dot);
        nrm = fmaf(acc2[i][1], acc2[i][1], nrm); dot = fmaf(acc2[i][1], qv.y, dot);
        nrm = fmaf(acc2[i][2], acc2[i][2], nrm); dot = fmaf(acc2[i][2], qv.z, dot);
        nrm = fmaf(acc2[i][3], acc2[i][3], nrm); dot = fmaf(acc2[i][3], qv.w, dot);
        #pragma unroll
        for (int m = 1; m < 64; m <<= 1) {
            nrm += __shfl_xor(nrm, m);
            dot += __shfl_xor(dot, m);
        }
        if (cg == 0) {
            const float qn_ = qnorm[n];
            sims[Rg] = dot / (qn_ * fmaxf(sqrtf(nrm), 1e-12f));
        }
        ushort4 pk;
        pk.x = f2bf_bits(acc2[i][0]);
        pk.y = f2bf_bits(acc2[i][1]);
        pk.z = f2bf_bits(acc2[i][2]);
        pk.w = f2bf_bits(acc2[i][3]);
        *(ushort4*)(ab + (size_t)Rg * DOUT + cg * 4) = pk;
    }
}

// ---- Kernel 2: per-n top-k + LN + cross-attention + output proj ----
__global__ __launch_bounds__(256)
void k_attn(const __hip_bfloat16* __restrict__ ab,
            const float* __restrict__ qraw,
            const float* __restrict__ sims,
            const float* __restrict__ lnqg, const float* __restrict__ lnqb,
            const float* __restrict__ lnkg, const float* __restrict__ lnkb,
            const float* __restrict__ Wq, const float* __restrict__ bq,
            const float* __restrict__ Wk, const float* __restrict__ bk,
            const float* __restrict__ Wv, const float* __restrict__ bv,
            const float* __restrict__ Wo, const float* __restrict__ bo,
            float* __restrict__ out)
{
    __shared__ float sKV[64 * 257];     // kv rows (raw then LN'd)
    __shared__ float sK [64 * 257];     // K proj, then reused for V proj
    __shared__ float ssim[256];
    __shared__ int   sflag[256];
    __shared__ int   ssel[64];
    __shared__ float sQln[256];
    __shared__ float sQp[256];
    __shared__ float sWatt[256];
    __shared__ float sO[256];
    __shared__ float smean[64], sinv[64];
    __shared__ float sred[8];

    const int t  = threadIdx.x;
    const int n  = blockIdx.x;
    const int cg = t & 63, rg = t >> 6;

    // phase 1: sims + query LN (on RAW query: LN is not scale-invariant due to eps)
    ssim[t] = (t < 196) ? sims[(size_t)n * 196 + t] : -3.0e38f;
    const float qv = qraw[(size_t)n * DOUT + t];
    float s1 = qv, s2 = qv * qv;
    #pragma unroll
    for (int m = 1; m < 64; m <<= 1) { s1 += __shfl_xor(s1, m); s2 += __shfl_xor(s2, m); }
    if ((t & 63) == 0) { sred[t >> 6] = s1; sred[4 + (t >> 6)] = s2; }
    __syncthreads();
    {
        const float mean = (sred[0] + sred[1] + sred[2] + sred[3]) * (1.f / 256.f);
        const float var  = (sred[4] + sred[5] + sred[6] + sred[7]) * (1.f / 256.f) - mean * mean;
        sQln[t] = (qv - mean) * rsqrtf(var + EPSV) * lnqg[t] + lnqb[t];
    }
    // phase 2: top-64 by rank counting (ties -> lower index, = lax.top_k set)
    int flag = 0;
    if (t < 196) {
        const float su = ssim[t];
        int rank = 0;
        for (int v = 0; v < 196; ++v) {
            const float sv = ssim[v];
            rank += (sv > su) || (sv == su && v < t);
        }
        flag = (rank < 64) ? 1 : 0;
    }
    sflag[t] = flag;
    __syncthreads();
    if (flag) {
        int pos = 0;
        for (int v = 0; v < t; ++v) pos += sflag[v];
        ssel[pos] = t;
    }
    __syncthreads();

    // phase 3: gather kv rows (bf16 -> fp32)
    for (int i = t; i < 64 * 256; i += 256) {
        const int s = i >> 8, c = i & 255;
        const int u = ssel[s];
        sKV[s * 257 + c] = __bfloat162float(ab[((size_t)n * 196 + u) * (size_t)DOUT + c]);
    }
    __syncthreads();
    // phase 4: LayerNorm rows
    if (t < 64) {
        float a1 = 0.f, a2 = 0.f;
        for (int c = 0; c < 256; ++c) {
            const float x = sKV[t * 257 + c];
            a1 += x; a2 = fmaf(x, x, a2);
        }
        const float m_ = a1 * (1.f / 256.f);
        const float v_ = a2 * (1.f / 256.f) - m_ * m_;
        smean[t] = m_;
        sinv[t]  = rsqrtf(v_ + EPSV);
    }
    __syncthreads();
    for (int i = t; i < 64 * 256; i += 256) {
        const int s = i >> 8, c = i & 255;
        sKV[s * 257 + c] = (sKV[s * 257 + c] - smean[s]) * sinv[s] * lnkg[c] + lnkb[c];
    }
    // phase 5: q projection (no barrier needed before: touches only sQln/sQp)
    {
        float acc = bq[t];
        for (int k = 0; k < 256; ++k)
            acc = fmaf(sQln[k], Wq[k * DOUT + t], acc);
        sQp[t] = acc;
    }
    __syncthreads();

    // phases 6/8: K and V projections [64x256] @ [256x256]
    auto projKV = [&](const float* __restrict__ Wm, const float* __restrict__ bm) {
        float bv4[4];
        #pragma unroll
        for (int jc = 0; jc < 4; ++jc) bv4[jc] = bm[cg + 64 * jc];
        float a16[16][4];
        #pragma unroll
        for (int ir = 0; ir < 16; ++ir)
            #pragma unroll
            for (int jc = 0; jc < 4; ++jc) a16[ir][jc] = bv4[jc];
        for (int k = 0; k < 256; ++k) {
            float wv[4];
            #pragma unroll
            for (int jc = 0; jc < 4; ++jc) wv[jc] = Wm[k * DOUT + cg + 64 * jc];
            #pragma unroll
            for (int ir = 0; ir < 16; ++ir) {
                const float av = sKV[(rg * 16 + ir) * 257 + k];
                #pragma unroll
                for (int jc = 0; jc < 4; ++jc)
                    a16[ir][jc] = fmaf(av, wv[jc], a16[ir][jc]);
            }
        }
        #pragma unroll
        for (int ir = 0; ir < 16; ++ir)
            #pragma unroll
            for (int jc = 0; jc < 4; ++jc)
                sK[(rg * 16 + ir) * 257 + cg + 64 * jc] = a16[ir][jc];
    };

    projKV(Wk, bk);
    __syncthreads();
    // phase 7: scores + softmax (wave rg = head, lane cg = kv slot)
    {
        const int h = rg, s = cg;
        float acc = 0.f;
        #pragma unroll
        for (int d = 0; d < 64; ++d)
            acc = fmaf(sQp[h * 64 + d], sK[s * 257 + h * 64 + d], acc);
        float sc = acc * 0.125f;        // 1/sqrt(64)
        float mx = sc;
        #pragma unroll
        for (int m = 1; m < 64; m <<= 1) mx = fmaxf(mx, __shfl_xor(mx, m));
        const float e = expf(sc - mx);
        float sum = e;
        #pragma unroll
        for (int m = 1; m < 64; m <<= 1) sum += __shfl_xor(sum, m);
        sWatt[t] = e / sum;
    }
    __syncthreads();                    // sK free now
    projKV(Wv, bv);                     // V into sK buffer
    __syncthreads();
    // phase 9: o = sum_s w[h][s] * V[s][h*64+d]
    {
        const int h = rg, d = cg;
        float acc = 0.f;
        #pragma unroll
        for (int s = 0; s < 64; ++s)
            acc = fmaf(sWatt[h * 64 + s], sK[s * 257 + h * 64 + d], acc);
        sO[t] = acc;
    }
    __syncthreads();
    // phase 10: output projection; valid_mask is all-true so row n -> out[n]
    {
        float acc = bo[t];
        for (int k = 0; k < 256; ++k)
            acc = fmaf(sO[k], Wo[k * DOUT + t], acc);
        out[(size_t)n * DOUT + t] = acc;
    }
}

extern "C" void kernel_launch(void* const* d_in, const int* in_sizes, int n_in,
                              void* d_out, int out_size, void* d_ws, size_t ws_size,
                              hipStream_t stream) {
    (void)in_sizes; (void)n_in; (void)out_size; (void)ws_size;
    const float* patches   = (const float*)d_in[0];
    const int*   patch_ids = (const int*)d_in[1];
    // d_in[2] valid_mask: all-true in this problem (scatter == identity); unused
    // d_in[3] patch_center_gps: unused by reference
    const int*   offsets   = (const int*)d_in[4];
    const float* W1 = (const float*)d_in[5];
    const float* b1 = (const float*)d_in[6];
    const float* W2 = (const float*)d_in[7];
    const float* b2 = (const float*)d_in[8];
    const float* lnqg = (const float*)d_in[9];
    const float* lnqb = (const float*)d_in[10];
    const float* lnkg = (const float*)d_in[11];
    const float* lnkb = (const float*)d_in[12];
    const float* Wq = (const float*)d_in[13];
    const float* bq = (const float*)d_in[14];
    const float* Wk = (const float*)d_in[15];
    const float* bk = (const float*)d_in[16];
    const float* Wv = (const float*)d_in[17];
    const float* bv = (const float*)d_in[18];
    const float* Wo = (const float*)d_in[19];
    const float* bo = (const float*)d_in[20];

    uint8_t* ws = (uint8_t*)d_ws;
    __hip_bfloat16* ab    = (__hip_bfloat16*)(ws);
    float*          qraw  = (float*)(ws + QRAW_OFF);
    float*          sims  = (float*)(ws + SIM_OFF);
    float*          qnorm = (float*)(ws + QNORM_OFF);
    float*          out   = (float*)d_out;

    hipLaunchKernelGGL(k_query, dim3(NCELL / 8), dim3(256), 0, stream,
                       patches, patch_ids, offsets, W1, b1, W2, b2, qraw, qnorm);
    hipLaunchKernelGGL(k_mlp, dim3((NCELL * UG) / 32), dim3(256), 0, stream,
                       patches, patch_ids, W1, b1, W2, b2, qraw, qnorm, ab, sims);
    hipLaunchKernelGGL(k_attn, dim3(NCELL), dim3(256), 0, stream,
                       ab, qraw, sims, lnqg, lnqb, lnkg, lnkb,
                       Wq, bq, Wk, bk, Wv, bv, Wo, bo, out);
}

// Round 4
// 4082.822 us; speedup vs baseline: 1.9319x; 1.9319x over previous
//
#include <hip/hip_runtime.h>
#include <hip/hip_bf16.h>
#include <stdint.h>

#define NCELL 2048
#define UG    196
#define DIN   384
#define DH    512
#define DOUT  256
#define EPSV  1e-5f

// ws layout (bytes)
#define AB_BYTES   205520896ull            // 401408*256*2  (a as bf16)
#define QRAW_OFF   AB_BYTES
#define QRAW_BYTES 2097152ull              // 2048*256*4    (raw query rows)
#define SIM_OFF    (QRAW_OFF + QRAW_BYTES)
#define SIM_BYTES  1605632ull              // 2048*196*4    (fp32 sims)
#define QNORM_OFF  (SIM_OFF + SIM_BYTES)   // 2048*4

static __device__ __forceinline__ unsigned short f2bf_bits(float x) {
    return __builtin_bit_cast(unsigned short, __float2bfloat16(x));
}

// ---------------- Kernel 1a: query rows (raw) + norms ----------------
__global__ __launch_bounds__(256)
void k_query(const float* __restrict__ patches, const int* __restrict__ patch_ids,
             const int* __restrict__ offsets,
             const float* __restrict__ W1, const float* __restrict__ b1,
             const float* __restrict__ W2, const float* __restrict__ b2,
             float* __restrict__ qraw, float* __restrict__ qnorm)
{
    __shared__ float sA[8 * DIN];
    __shared__ float sH[8 * DH];
    __shared__ float sPart[4 * 8];
    __shared__ int   sSrc[8];
    const int t  = threadIdx.x;
    const int nb = blockIdx.x * 8;
    if (t < 8) {
        int n  = nb + t;
        int ox = offsets[2 * n + 0];
        int oy = offsets[2 * n + 1];
        int it = min(max(7 + oy, 0), 13);
        int jt = min(max(7 + ox, 0), 13);
        sSrc[t] = patch_ids[n] * 196 + it * 14 + jt;
    }
    __syncthreads();
    #pragma unroll
    for (int i = 0; i < 3; ++i) {
        int fi = t + 256 * i;               // < 768 = 8 rows * 96 float4
        int r = fi / 96, c4 = fi % 96;
        const float4 v = ((const float4*)(patches + (size_t)sSrc[r] * DIN))[c4];
        ((float4*)(sA + r * DIN))[c4] = v;
    }
    __syncthreads();
    float h0[8], h1[8];
    {
        const float bb0 = b1[t], bb1 = b1[t + 256];
        #pragma unroll
        for (int r = 0; r < 8; ++r) { h0[r] = bb0; h1[r] = bb1; }
    }
    for (int k = 0; k < DIN; ++k) {
        const float w0 = W1[k * DH + t];
        const float w1 = W1[k * DH + t + 256];
        #pragma unroll
        for (int r = 0; r < 8; ++r) {
            const float av = sA[r * DIN + k];
            h0[r] = fmaf(av, w0, h0[r]);
            h1[r] = fmaf(av, w1, h1[r]);
        }
    }
    #pragma unroll
    for (int r = 0; r < 8; ++r) {
        float v0 = h0[r]; v0 = v0 >= 0.f ? v0 : 0.01f * v0;
        float v1 = h1[r]; v1 = v1 >= 0.f ? v1 : 0.01f * v1;
        sH[r * DH + t]       = v0;
        sH[r * DH + t + 256] = v1;
    }
    __syncthreads();
    float a8[8];
    {
        const float bb = b2[t];
        #pragma unroll
        for (int r = 0; r < 8; ++r) a8[r] = bb;
    }
    for (int k = 0; k < DH; ++k) {
        const float w = W2[k * DOUT + t];
        #pragma unroll
        for (int r = 0; r < 8; ++r) a8[r] = fmaf(sH[r * DH + k], w, a8[r]);
    }
    const int wid = t >> 6;
    #pragma unroll
    for (int r = 0; r < 8; ++r) {
        float p = a8[r] * a8[r];
        #pragma unroll
        for (int m = 1; m < 64; m <<= 1) p += __shfl_xor(p, m);
        if ((t & 63) == 0) sPart[wid * 8 + r] = p;
    }
    __syncthreads();
    if (t < 8) {
        float s = sPart[t] + sPart[8 + t] + sPart[16 + t] + sPart[24 + t];
        qnorm[nb + t] = fmaxf(sqrtf(s), 1e-12f);
    }
    #pragma unroll
    for (int r = 0; r < 8; ++r)
        qraw[(size_t)(nb + r) * DOUT + t] = a8[r];
}

// -------- Kernel 1b: fused gather + MLP + sim epilogue + bf16 a ------
// v3: transposed + XOR-swizzled LDS operand tiles.
//     sT[k*32 + (r ^ 4*((k>>3)&7))] holds A^T (k<384) then H^T (k<512).
//     Per K-step: A = 2 lane-invariant ds_read_b128 broadcasts,
//                 W = 2 (GEMM1) / 1 (GEMM2) ds_read_b128. No cross-loop
//     register prefetch (round-2's spill source).
__global__ __launch_bounds__(256)
void k_mlp(const float* __restrict__ patches, const int* __restrict__ patch_ids,
           const float* __restrict__ W1, const float* __restrict__ b1,
           const float* __restrict__ W2, const float* __restrict__ b2,
           const float* __restrict__ qraw, const float* __restrict__ qnorm,
           __hip_bfloat16* __restrict__ ab, float* __restrict__ sims)
{
    __shared__ __align__(16) float sT[512 * 32];   // 64KB: A^T then H^T (swizzled)
    __shared__ __align__(16) float sW[4096];       // 16KB W chunk
    const int t  = threadIdx.x;
    const int cg = t & 63;
    const int rg = t >> 6;
    const int R0 = blockIdx.x * 32;

    // ---- stage A^T: 32 rows x 384 k, transposed with XOR swizzle ----
    // group f: fcol = f%96 (float4-col), r0 = 4*(f/96) (4-row group)
    #pragma unroll
    for (int g = 0; g < 3; ++g) {
        const int f    = t + 256 * g;       // < 768
        const int fcol = f % 96;
        const int r0   = 4 * (f / 96);
        float4 v0, v1, v2, v3;
        {
            int Rg = R0 + r0;
            int n = Rg / 196, u = Rg - n * 196;
            v0 = ((const float4*)(patches + ((size_t)patch_ids[n] * 196 + u) * DIN))[fcol];
            Rg = R0 + r0 + 1; n = Rg / 196; u = Rg - n * 196;
            v1 = ((const float4*)(patches + ((size_t)patch_ids[n] * 196 + u) * DIN))[fcol];
            Rg = R0 + r0 + 2; n = Rg / 196; u = Rg - n * 196;
            v2 = ((const float4*)(patches + ((size_t)patch_ids[n] * 196 + u) * DIN))[fcol];
            Rg = R0 + r0 + 3; n = Rg / 196; u = Rg - n * 196;
            v3 = ((const float4*)(patches + ((size_t)patch_ids[n] * 196 + u) * DIN))[fcol];
        }
        const int sw = 4 * ((fcol >> 1) & 7);
        const int rr = r0 ^ sw;             // contiguous 4-run base
        const int k0 = 4 * fcol;
        *(float4*)&sT[(k0 + 0) * 32 + rr] = make_float4(v0.x, v1.x, v2.x, v3.x);
        *(float4*)&sT[(k0 + 1) * 32 + rr] = make_float4(v0.y, v1.y, v2.y, v3.y);
        *(float4*)&sT[(k0 + 2) * 32 + rr] = make_float4(v0.z, v1.z, v2.z, v3.z);
        *(float4*)&sT[(k0 + 3) * 32 + rr] = make_float4(v0.w, v1.w, v2.w, v3.w);
    }

    float acc1[8][8];   // 8 rows x {cols cg*4+j (j<4), 256+cg*4+(j-4)}
    #pragma unroll
    for (int i = 0; i < 8; ++i)
        #pragma unroll
        for (int j = 0; j < 8; ++j) acc1[i][j] = 0.f;

    // GEMM1: 32x512 += A(32x384) @ W1(384x512), K-chunks of 8
    for (int kc = 0; kc < 48; ++kc) {
        __syncthreads();
        #pragma unroll
        for (int i = 0; i < 4; ++i)
            ((float4*)sW)[t + 256 * i] =
                ((const float4*)(W1 + (size_t)kc * 8 * DH))[t + 256 * i];
        __syncthreads();
        const int swk   = 4 * (kc & 7);         // = 4*((k>>3)&7) for this chunk
        const int rbase = (rg * 8) ^ (swk & 24);
        const int lof   = swk & 4;
        #pragma unroll
        for (int kk = 0; kk < 8; ++kk) {
            const int ka = (kc * 8 + kk) * 32 + rbase;
            const float4 alo = *(const float4*)&sT[ka + lof];        // rows rg*8..+3
            const float4 ahi = *(const float4*)&sT[ka + (lof ^ 4)];  // rows +4..+7
            const float4 w0 = *(const float4*)&sW[kk * DH + cg * 4];
            const float4 w1 = *(const float4*)&sW[kk * DH + 256 + cg * 4];
            const float a_[8] = {alo.x, alo.y, alo.z, alo.w, ahi.x, ahi.y, ahi.z, ahi.w};
            #pragma unroll
            for (int i = 0; i < 8; ++i) {
                acc1[i][0] = fmaf(a_[i], w0.x, acc1[i][0]);
                acc1[i][1] = fmaf(a_[i], w0.y, acc1[i][1]);
                acc1[i][2] = fmaf(a_[i], w0.z, acc1[i][2]);
                acc1[i][3] = fmaf(a_[i], w0.w, acc1[i][3]);
                acc1[i][4] = fmaf(a_[i], w1.x, acc1[i][4]);
                acc1[i][5] = fmaf(a_[i], w1.y, acc1[i][5]);
                acc1[i][6] = fmaf(a_[i], w1.z, acc1[i][6]);
                acc1[i][7] = fmaf(a_[i], w1.w, acc1[i][7]);
            }
        }
    }

    // bias + LeakyReLU in-register
    {
        const float4 b1f0 = ((const float4*)b1)[cg];
        const float4 b1f1 = ((const float4*)b1)[64 + cg];
        #pragma unroll
        for (int i = 0; i < 8; ++i) {
            acc1[i][0] += b1f0.x; acc1[i][1] += b1f0.y;
            acc1[i][2] += b1f0.z; acc1[i][3] += b1f0.w;
            acc1[i][4] += b1f1.x; acc1[i][5] += b1f1.y;
            acc1[i][6] += b1f1.z; acc1[i][7] += b1f1.w;
            #pragma unroll
            for (int j = 0; j < 8; ++j)
                acc1[i][j] = acc1[i][j] >= 0.f ? acc1[i][j] : 0.01f * acc1[i][j];
        }
    }
    __syncthreads();                    // all waves done reading sT(A) & sW(W1)

    // ---- write H^T (swizzled, b128 along rows) ----
    {
        const int swc = 4 * ((cg >> 1) & 7);   // = 4*((c>>3)&7) for c=cg*4+j (+256h)
        const int rb  = (rg * 8) ^ (swc & 24);
        const int plo = rb + (swc & 4);
        const int phi = rb + ((swc & 4) ^ 4);
        #pragma unroll
        for (int h = 0; h < 2; ++h)
            #pragma unroll
            for (int j = 0; j < 4; ++j) {
                const int c = h * 256 + cg * 4 + j;
                *(float4*)&sT[c * 32 + plo] =
                    make_float4(acc1[0][h*4+j], acc1[1][h*4+j], acc1[2][h*4+j], acc1[3][h*4+j]);
                *(float4*)&sT[c * 32 + phi] =
                    make_float4(acc1[4][h*4+j], acc1[5][h*4+j], acc1[6][h*4+j], acc1[7][h*4+j]);
            }
    }

    float acc2[8][4];                  // 8 rows x 4 consecutive cols (c = cg*4+j)
    #pragma unroll
    for (int i = 0; i < 8; ++i)
        #pragma unroll
        for (int j = 0; j < 4; ++j) acc2[i][j] = 0.f;

    // GEMM2: 32x256 += H(32x512) @ W2(512x256), K-chunks of 16
    for (int kc = 0; kc < 32; ++kc) {
        __syncthreads();
        #pragma unroll
        for (int i = 0; i < 4; ++i)
            ((float4*)sW)[t + 256 * i] =
                ((const float4*)(W2 + (size_t)kc * 16 * DOUT))[t + 256 * i];
        __syncthreads();
        #pragma unroll
        for (int kh = 0; kh < 2; ++kh) {
            const int swk   = 4 * ((kc * 2 + kh) & 7);
            const int rbase = (rg * 8) ^ (swk & 24);
            const int lof   = swk & 4;
            #pragma unroll
            for (int kk = 0; kk < 8; ++kk) {
                const int k  = kc * 16 + kh * 8 + kk;
                const float4 alo = *(const float4*)&sT[k * 32 + rbase + lof];
                const float4 ahi = *(const float4*)&sT[k * 32 + rbase + (lof ^ 4)];
                const float4 w0  = *(const float4*)&sW[(kh * 8 + kk) * DOUT + cg * 4];
                const float a_[8] = {alo.x, alo.y, alo.z, alo.w, ahi.x, ahi.y, ahi.z, ahi.w};
                #pragma unroll
                for (int i = 0; i < 8; ++i) {
                    acc2[i][0] = fmaf(a_[i], w0.x, acc2[i][0]);
                    acc2[i][1] = fmaf(a_[i], w0.y, acc2[i][1]);
                    acc2[i][2] = fmaf(a_[i], w0.z, acc2[i][2]);
                    acc2[i][3] = fmaf(a_[i], w0.w, acc2[i][3]);
                }
            }
        }
    }

    {
        const float4 b2f = ((const float4*)b2)[cg];
        #pragma unroll
        for (int i = 0; i < 8; ++i) {
            acc2[i][0] += b2f.x; acc2[i][1] += b2f.y;
            acc2[i][2] += b2f.z; acc2[i][3] += b2f.w;
        }
    }

    // epilogue: fp32 cosine sim vs query + bf16 store of a
    #pragma unroll
    for (int i = 0; i < 8; ++i) {
        const int Rg = R0 + rg * 8 + i;
        const int n  = Rg / 196;
        const float4 qv = ((const float4*)(qraw + (size_t)n * DOUT))[cg];
        float nrm = 0.f, dot = 0.f;
        nrm = fmaf(acc2[i][0], acc2[i][0], nrm); dot = fmaf(acc2[i][0], qv.x, dot);
        nrm = fmaf(acc2[i][1], acc2[i][1], nrm); dot = fmaf(acc2[i][1], qv.y, dot);
        nrm = fmaf(acc2[i][2], acc2[i][2], nrm); dot = fmaf(acc2[i][2], qv.z, dot);
        nrm = fmaf(acc2[i][3], acc2[i][3], nrm); dot = fmaf(acc2[i][3], qv.w, dot);
        #pragma unroll
        for (int m = 1; m < 64; m <<= 1) {
            nrm += __shfl_xor(nrm, m);
            dot += __shfl_xor(dot, m);
        }
        if (cg == 0) {
            const float qn_ = qnorm[n];
            sims[Rg] = dot / (qn_ * fmaxf(sqrtf(nrm), 1e-12f));
        }
        ushort4 pk;
        pk.x = f2bf_bits(acc2[i][0]);
        pk.y = f2bf_bits(acc2[i][1]);
        pk.z = f2bf_bits(acc2[i][2]);
        pk.w = f2bf_bits(acc2[i][3]);
        *(ushort4*)(ab + (size_t)Rg * DOUT + cg * 4) = pk;
    }
}

// ---- Kernel 2: per-n top-k + LN + cross-attention + output proj ----
__global__ __launch_bounds__(256)
void k_attn(const __hip_bfloat16* __restrict__ ab,
            const float* __restrict__ qraw,
            const float* __restrict__ sims,
            const float* __restrict__ lnqg, const float* __restrict__ lnqb,
            const float* __restrict__ lnkg, const float* __restrict__ lnkb,
            const float* __restrict__ Wq, const float* __restrict__ bq,
            const float* __restrict__ Wk, const float* __restrict__ bk,
            const float* __restrict__ Wv, const float* __restrict__ bv,
            const float* __restrict__ Wo, const float* __restrict__ bo,
            float* __restrict__ out)
{
    __shared__ float sKV[64 * 257];     // kv rows (raw then LN'd)
    __shared__ float sK [64 * 257];     // K proj, then reused for V proj
    __shared__ float ssim[256];
    __shared__ int   sflag[256];
    __shared__ int   ssel[64];
    __shared__ float sQln[256];
    __shared__ float sQp[256];
    __shared__ float sWatt[256];
    __shared__ float sO[256];
    __shared__ float smean[64], sinv[64];
    __shared__ float sred[8];

    const int t  = threadIdx.x;
    const int n  = blockIdx.x;
    const int cg = t & 63, rg = t >> 6;

    // phase 1: sims + query LN (on RAW query: LN is not scale-invariant due to eps)
    ssim[t] = (t < 196) ? sims[(size_t)n * 196 + t] : -3.0e38f;
    const float qv = qraw[(size_t)n * DOUT + t];
    float s1 = qv, s2 = qv * qv;
    #pragma unroll
    for (int m = 1; m < 64; m <<= 1) { s1 += __shfl_xor(s1, m); s2 += __shfl_xor(s2, m); }
    if ((t & 63) == 0) { sred[t >> 6] = s1; sred[4 + (t >> 6)] = s2; }
    __syncthreads();
    {
        const float mean = (sred[0] + sred[1] + sred[2] + sred[3]) * (1.f / 256.f);
        const float var  = (sred[4] + sred[5] + sred[6] + sred[7]) * (1.f / 256.f) - mean * mean;
        sQln[t] = (qv - mean) * rsqrtf(var + EPSV) * lnqg[t] + lnqb[t];
    }
    // phase 2: top-64 by rank counting (ties -> lower index, = lax.top_k set)
    int flag = 0;
    if (t < 196) {
        const float su = ssim[t];
        int rank = 0;
        for (int v = 0; v < 196; ++v) {
            const float sv = ssim[v];
            rank += (sv > su) || (sv == su && v < t);
        }
        flag = (rank < 64) ? 1 : 0;
    }
    sflag[t] = flag;
    __syncthreads();
    if (flag) {
        int pos = 0;
        for (int v = 0; v < t; ++v) pos += sflag[v];
        ssel[pos] = t;
    }
    __syncthreads();

    // phase 3: gather kv rows (bf16 -> fp32)
    for (int i = t; i < 64 * 256; i += 256) {
        const int s = i >> 8, c = i & 255;
        const int u = ssel[s];
        sKV[s * 257 + c] = __bfloat162float(ab[((size_t)n * 196 + u) * (size_t)DOUT + c]);
    }
    __syncthreads();
    // phase 4: LayerNorm rows
    if (t < 64) {
        float a1 = 0.f, a2 = 0.f;
        for (int c = 0; c < 256; ++c) {
            const float x = sKV[t * 257 + c];
            a1 += x; a2 = fmaf(x, x, a2);
        }
        const float m_ = a1 * (1.f / 256.f);
        const float v_ = a2 * (1.f / 256.f) - m_ * m_;
        smean[t] = m_;
        sinv[t]  = rsqrtf(v_ + EPSV);
    }
    __syncthreads();
    for (int i = t; i < 64 * 256; i += 256) {
        const int s = i >> 8, c = i & 255;
        sKV[s * 257 + c] = (sKV[s * 257 + c] - smean[s]) * sinv[s] * lnkg[c] + lnkb[c];
    }
    // phase 5: q projection (no barrier needed before: touches only sQln/sQp)
    {
        float acc = bq[t];
        for (int k = 0; k < 256; ++k)
            acc = fmaf(sQln[k], Wq[k * DOUT + t], acc);
        sQp[t] = acc;
    }
    __syncthreads();

    // phases 6/8: K and V projections [64x256] @ [256x256]
    auto projKV = [&](const float* __restrict__ Wm, const float* __restrict__ bm) {
        float bv4[4];
        #pragma unroll
        for (int jc = 0; jc < 4; ++jc) bv4[jc] = bm[cg + 64 * jc];
        float a16[16][4];
        #pragma unroll
        for (int ir = 0; ir < 16; ++ir)
            #pragma unroll
            for (int jc = 0; jc < 4; ++jc) a16[ir][jc] = bv4[jc];
        for (int k = 0; k < 256; ++k) {
            float wv[4];
            #pragma unroll
            for (int jc = 0; jc < 4; ++jc) wv[jc] = Wm[k * DOUT + cg + 64 * jc];
            #pragma unroll
            for (int ir = 0; ir < 16; ++ir) {
                const float av = sKV[(rg * 16 + ir) * 257 + k];
                #pragma unroll
                for (int jc = 0; jc < 4; ++jc)
                    a16[ir][jc] = fmaf(av, wv[jc], a16[ir][jc]);
            }
        }
        #pragma unroll
        for (int ir = 0; ir < 16; ++ir)
            #pragma unroll
            for (int jc = 0; jc < 4; ++jc)
                sK[(rg * 16 + ir) * 257 + cg + 64 * jc] = a16[ir][jc];
    };

    projKV(Wk, bk);
    __syncthreads();
    // phase 7: scores + softmax (wave rg = head, lane cg = kv slot)
    {
        const int h = rg, s = cg;
        float acc = 0.f;
        #pragma unroll
        for (int d = 0; d < 64; ++d)
            acc = fmaf(sQp[h * 64 + d], sK[s * 257 + h * 64 + d], acc);
        float sc = acc * 0.125f;        // 1/sqrt(64)
        float mx = sc;
        #pragma unroll
        for (int m = 1; m < 64; m <<= 1) mx = fmaxf(mx, __shfl_xor(mx, m));
        const float e = expf(sc - mx);
        float sum = e;
        #pragma unroll
        for (int m = 1; m < 64; m <<= 1) sum += __shfl_xor(sum, m);
        sWatt[t] = e / sum;
    }
    __syncthreads();                    // sK free now
    projKV(Wv, bv);                     // V into sK buffer
    __syncthreads();
    // phase 9: o = sum_s w[h][s] * V[s][h*64+d]
    {
        const int h = rg, d = cg;
        float acc = 0.f;
        #pragma unroll
        for (int s = 0; s < 64; ++s)
            acc = fmaf(sWatt[h * 64 + s], sK[s * 257 + h * 64 + d], acc);
        sO[t] = acc;
    }
    __syncthreads();
    // phase 10: output projection; valid_mask is all-true so row n -> out[n]
    {
        float acc = bo[t];
        for (int k = 0; k < 256; ++k)
            acc = fmaf(sO[k], Wo[k * DOUT + t], acc);
        out[(size_t)n * DOUT + t] = acc;
    }
}

extern "C" void kernel_launch(void* const* d_in, const int* in_sizes, int n_in,
                              void* d_out, int out_size, void* d_ws, size_t ws_size,
                              hipStream_t stream) {
    (void)in_sizes; (void)n_in; (void)out_size; (void)ws_size;
    const float* patches   = (const float*)d_in[0];
    const int*   patch_ids = (const int*)d_in[1];
    // d_in[2] valid_mask: all-true in this problem (scatter == identity); unused
    // d_in[3] patch_center_gps: unused by reference
    const int*   offsets   = (const int*)d_in[4];
    const float* W1 = (const float*)d_in[5];
    const float* b1 = (const float*)d_in[6];
    const float* W2 = (const float*)d_in[7];
    const float* b2 = (const float*)d_in[8];
    const float* lnqg = (const float*)d_in[9];
    const float* lnqb = (const float*)d_in[10];
    const float* lnkg = (const float*)d_in[11];
    const float* lnkb = (const float*)d_in[12];
    const float* Wq = (const float*)d_in[13];
    const float* bq = (const float*)d_in[14];
    const float* Wk = (const float*)d_in[15];
    const float* bk = (const float*)d_in[16];
    const float* Wv = (const float*)d_in[17];
    const float* bv = (const float*)d_in[18];
    const float* Wo = (const float*)d_in[19];
    const float* bo = (const float*)d_in[20];

    uint8_t* ws = (uint8_t*)d_ws;
    __hip_bfloat16* ab    = (__hip_bfloat16*)(ws);
    float*          qraw  = (float*)(ws + QRAW_OFF);
    float*          sims  = (float*)(ws + SIM_OFF);
    float*          qnorm = (float*)(ws + QNORM_OFF);
    float*          out   = (float*)d_out;

    hipLaunchKernelGGL(k_query, dim3(NCELL / 8), dim3(256), 0, stream,
                       patches, patch_ids, offsets, W1, b1, W2, b2, qraw, qnorm);
    hipLaunchKernelGGL(k_mlp, dim3((NCELL * UG) / 32), dim3(256), 0, stream,
                       patches, patch_ids, W1, b1, W2, b2, qraw, qnorm, ab, sims);
    hipLaunchKernelGGL(k_attn, dim3(NCELL), dim3(256), 0, stream,
                       ab, qraw, sims, lnqg, lnqb, lnkg, lnkb,
                       Wq, bq, Wk, bk, Wv, bv, Wo, bo, out);
}